// Round 6
// baseline (372.653 us; speedup 1.0000x reference)
//
#include <hip/hip_runtime.h>

// Parametric Multichannel Wiener Filter, MI355X single fused kernel, v3.
// B=4, C=8, F=512, T=1000. One block per (b,f): 2048 blocks x 256 threads.
// v3 = v2 (4-pass t-staging ~29.7 KB LDS -> 4 blocks/CU, register-tiled
// conflict-free PSD, apply from global with G in registers) but with the
// solve path reverted to v1's BARRIERED block-wide Gauss-Jordan (proven
// correct round 4). v2's barrier-free wave-lockstep solve gave absmax 0.086.

#define NB 4
#define NC 8
#define NF 512
#define NT 1000
#define CH ((size_t)(NF * NT))   // x channel stride in floats
#define PASS_T 256
#define XSTR 258                 // float2 stride per channel row in LDS tile

__global__ __launch_bounds__(256, 4) void pmwf_kernel(
    const float* __restrict__ xre, const float* __restrict__ xim,
    const float* __restrict__ msk_s, const float* __restrict__ msk_n,
    float* __restrict__ out, int real_only)
{
    __shared__ float2 xs[NC * XSTR];    // 16,512 B  x tile (one 256-t pass)
    __shared__ float2 msn[NT];          //  8,000 B  (mask_s, mask_n) per t
    __shared__ float2 M[8][16];         //  1,024 B  augmented [A|B]; cols 0..7 later hold G
    __shared__ float  scr[4][16][16];   //  4,096 B  cross-wave PSD reduce
    __shared__ float2 invs;
    __shared__ float2 redscr[4];

    const int tid  = threadIdx.x;
    const int lane = tid & 63;
    const int wave = tid >> 6;
    const int bid  = blockIdx.x;
    const int b = bid >> 9;
    const int f = bid & 511;

    const size_t mbase = ((size_t)b * NF + f) * NT;
    const size_t xbase = (size_t)b * NC * CH + (size_t)f * NT;  // + c*CH + t

    // ---------------- phase 0: masks -> LDS + sums ----------------
    float2 psum = make_float2(0.f, 0.f);
    if (tid < 250) {
        const int t0 = tid * 4;
        float4 s4 = *(const float4*)(msk_s + mbase + t0);
        float4 n4 = *(const float4*)(msk_n + mbase + t0);
        psum.x = s4.x + s4.y + s4.z + s4.w;
        psum.y = n4.x + n4.y + n4.z + n4.w;
        msn[t0 + 0] = make_float2(s4.x, n4.x);
        msn[t0 + 1] = make_float2(s4.y, n4.y);
        msn[t0 + 2] = make_float2(s4.z, n4.z);
        msn[t0 + 3] = make_float2(s4.w, n4.w);
    }
#pragma unroll
    for (int d = 1; d < 64; d <<= 1) {
        psum.x += __shfl_xor(psum.x, d);
        psum.y += __shfl_xor(psum.y, d);
    }
    if (lane == 0) redscr[wave] = psum;
    __syncthreads();
    if (tid == 0) {
        float ss = redscr[0].x + redscr[1].x + redscr[2].x + redscr[3].x;
        float sn = redscr[0].y + redscr[1].y + redscr[2].y + redscr[3].y;
        invs = make_float2(1.f / (ss + 1e-10f), 1.f / (sn + 1e-10f));
    }

    // ---------------- PSD: 4 passes of 256 t ----------------
    // thread = (tile, chunk): tile = tid&15 -> 2x2 channel-pair tile
    //                         chunk = tid>>4 in [0,16), t_local = i*16+chunk
    const int tile  = tid & 15;
    const int chunk = tid >> 4;
    const int pcb = (tile >> 2) * 2;    // 'a' rows: pcb, pcb+1
    const int peb = (tile & 3) * 2;     // 'e' rows: peb, peb+1

    float aNr[4] = {0,0,0,0}, aNi[4] = {0,0,0,0};
    float aSr[4] = {0,0,0,0}, aSi[4] = {0,0,0,0};

    for (int p = 0; p < 4; ++p) {
        const int tbeg  = p * PASS_T;
        const int tpass = (p == 3) ? (NT - 3 * PASS_T) : PASS_T;  // 256,256,256,232
        __syncthreads();   // previous pass fully consumed before overwrite
        // stage x[tbeg : tbeg+tpass) -> xs  (512 float4-pairs, 2 per thread)
#pragma unroll
        for (int k = 0; k < 2; ++k) {
            const int q = tid + (k << 8);
            const int c = q >> 6;
            const int tq = (q & 63) << 2;
            if (tq < tpass) {
                float4 r4 = *(const float4*)(xre + xbase + c * CH + tbeg + tq);
                float4 i4 = *(const float4*)(xim + xbase + c * CH + tbeg + tq);
                float2* xp = &xs[c * XSTR + tq];
                xp[0] = make_float2(r4.x, i4.x);
                xp[1] = make_float2(r4.y, i4.y);
                xp[2] = make_float2(r4.z, i4.z);
                xp[3] = make_float2(r4.w, i4.w);
            }
        }
        __syncthreads();
        // accumulate 4 pairs x 16 t per thread (t strided by 16 -> conflict-free)
#pragma unroll
        for (int i = 0; i < 16; ++i) {
            const int tl = (i << 4) + chunk;
            if (tl < tpass) {
                float2 m2 = msn[tbeg + tl];
                float2 a0 = xs[(pcb + 0) * XSTR + tl];
                float2 a1 = xs[(pcb + 1) * XSTR + tl];
                float2 e0 = xs[(peb + 0) * XSTR + tl];
                float2 e1 = xs[(peb + 1) * XSTR + tl];
                // pair j: a = pcb+(j>>1), e = peb+(j&1); prod = a*conj(e)
                {   float pr = a0.x*e0.x + a0.y*e0.y, pi = a0.y*e0.x - a0.x*e0.y;
                    aSr[0] += m2.x*pr; aSi[0] += m2.x*pi; aNr[0] += m2.y*pr; aNi[0] += m2.y*pi; }
                {   float pr = a0.x*e1.x + a0.y*e1.y, pi = a0.y*e1.x - a0.x*e1.y;
                    aSr[1] += m2.x*pr; aSi[1] += m2.x*pi; aNr[1] += m2.y*pr; aNi[1] += m2.y*pi; }
                {   float pr = a1.x*e0.x + a1.y*e0.y, pi = a1.y*e0.x - a1.x*e0.y;
                    aSr[2] += m2.x*pr; aSi[2] += m2.x*pi; aNr[2] += m2.y*pr; aNi[2] += m2.y*pi; }
                {   float pr = a1.x*e1.x + a1.y*e1.y, pi = a1.y*e1.x - a1.x*e1.y;
                    aSr[3] += m2.x*pr; aSi[3] += m2.x*pi; aNr[3] += m2.y*pr; aNi[3] += m2.y*pi; }
            }
        }
    }

    // ---------------- reduce over chunks ----------------
    // within-wave chunk bits are lane bits 4,5
#pragma unroll
    for (int j = 0; j < 4; ++j) {
        aNr[j] += __shfl_xor(aNr[j], 16); aNr[j] += __shfl_xor(aNr[j], 32);
        aNi[j] += __shfl_xor(aNi[j], 16); aNi[j] += __shfl_xor(aNi[j], 32);
        aSr[j] += __shfl_xor(aSr[j], 16); aSr[j] += __shfl_xor(aSr[j], 32);
        aSi[j] += __shfl_xor(aSi[j], 16); aSi[j] += __shfl_xor(aSi[j], 32);
    }
    if (lane < 16) {   // lane == tile for lane<16
#pragma unroll
        for (int j = 0; j < 4; ++j) {
            scr[wave][lane][j * 4 + 0] = aNr[j];
            scr[wave][lane][j * 4 + 1] = aNi[j];
            scr[wave][lane][j * 4 + 2] = aSr[j];
            scr[wave][lane][j * 4 + 3] = aSi[j];
        }
    }
    __syncthreads();
    {   // final cross-wave combine: one (tile,slot) per thread -> M
        const int t2 = tid >> 4, slot = tid & 15;
        float v = scr[0][t2][slot] + scr[1][t2][slot] + scr[2][t2][slot] + scr[3][t2][slot];
        const int j = slot >> 2, kind = slot & 3;
        const int pc = (t2 >> 2) * 2 + (j >> 1);
        const int pe = (t2 & 3) * 2 + (j & 1);
        float* Mf = (float*)M;
        const float2 iv = invs;
        const int baseN = (pc * 16 + pe) * 2;       // A = psd_n
        const int baseS = (pc * 16 + pe + 8) * 2;   // B = psd_s
        if      (kind == 0) Mf[baseN + 0] = v * iv.y;
        else if (kind == 1) Mf[baseN + 1] = v * iv.y;
        else if (kind == 2) Mf[baseS + 0] = v * iv.x;
        else                Mf[baseS + 1] = v * iv.x;
    }
    __syncthreads();

    // ---------------- diagonal regularization (barriered, v1) ----------------
    float dreg;
    {
        float trn = 0.f;
#pragma unroll
        for (int k = 0; k < 8; ++k) trn += M[k][k].x;
        dreg = 1e-6f * trn + 1e-8f;
    }
    __syncthreads();
    if (tid < 8) M[tid][tid].x += dreg;
    __syncthreads();

    // ---------------- Gauss-Jordan: [A|B] -> [I|A^-1 B]  (barriered, v1) ----
    {
        const int r = tid >> 4, jc = tid & 15;
        const bool act = tid < 128;
#pragma unroll
        for (int k = 0; k < 8; ++k) {
            float2 newkj;
            if (act && r == k) {
                float2 p = M[k][k];
                float ip = 1.f / (p.x * p.x + p.y * p.y);
                float2 v = M[k][jc];
                newkj = make_float2((v.x * p.x + v.y * p.y) * ip,
                                    (v.y * p.x - v.x * p.y) * ip);
            }
            __syncthreads();
            if (act && r == k) M[k][jc] = newkj;
            __syncthreads();
            float2 fr, pv, cur;
            if (act) { fr = M[r][k]; pv = M[k][jc]; cur = M[r][jc]; }
            __syncthreads();
            if (act && r != k) {
                M[r][jc] = make_float2(cur.x - (fr.x * pv.x - fr.y * pv.y),
                                       cur.y - (fr.x * pv.y + fr.y * pv.x));
            }
            __syncthreads();
        }
    }

    // ---------------- W = X/(1+tr); overlay G[m][c]=conj(W[c][m]) (v1) ------
    {
        float2 tr = make_float2(1.f, 0.f);   // BETA + trace(num)
#pragma unroll
        for (int k = 0; k < 8; ++k) { tr.x += M[k][k + 8].x; tr.y += M[k][k + 8].y; }
        float idn = 1.f / (tr.x * tr.x + tr.y * tr.y);
        float2 invd = make_float2(tr.x * idn, -tr.y * idn);
        if (tid < 64) {
            int m = tid & 7, c = tid >> 3;
            float2 v = M[c][m + 8];          // read cols 8..15
            // W = v*invd ; G = conj(W)  -> write cols 0..7 (disjoint, race-free)
            M[m][c] = make_float2(v.x * invd.x - v.y * invd.y,
                                  -(v.x * invd.y + v.y * invd.x));
        }
    }
    __syncthreads();

    // ---------------- apply: wave w -> m = 2w, 2w+1; x from global (L2-hot) ----
    {
        const int m0 = wave * 2, m1 = m0 + 1;
        float2 g0[8], g1[8];
#pragma unroll
        for (int c = 0; c < 8; ++c) { g0[c] = M[m0][c]; g1[c] = M[m1][c]; }
        if (real_only) {
            for (int it = 0; it < 16; ++it) {
                const int t = (it << 6) + lane;
                if (t < NT) {
                    float r0 = 0.f, r1 = 0.f;
#pragma unroll
                    for (int c = 0; c < 8; ++c) {
                        float vr = xre[xbase + c * CH + t];
                        float vi = xim[xbase + c * CH + t];
                        r0 += g0[c].x * vr - g0[c].y * vi;
                        r1 += g1[c].x * vr - g1[c].y * vi;
                    }
                    out[xbase + (size_t)m0 * CH + t] = r0;
                    out[xbase + (size_t)m1 * CH + t] = r1;
                }
            }
        } else {
            float2* outc = (float2*)out;
            for (int it = 0; it < 16; ++it) {
                const int t = (it << 6) + lane;
                if (t < NT) {
                    float r0 = 0.f, i0 = 0.f, r1 = 0.f, i1 = 0.f;
#pragma unroll
                    for (int c = 0; c < 8; ++c) {
                        float vr = xre[xbase + c * CH + t];
                        float vi = xim[xbase + c * CH + t];
                        r0 += g0[c].x * vr - g0[c].y * vi;
                        i0 += g0[c].x * vi + g0[c].y * vr;
                        r1 += g1[c].x * vr - g1[c].y * vi;
                        i1 += g1[c].x * vi + g1[c].y * vr;
                    }
                    outc[xbase + (size_t)m0 * CH + t] = make_float2(r0, i0);
                    outc[xbase + (size_t)m1 * CH + t] = make_float2(r1, i1);
                }
            }
        }
    }
}

extern "C" void kernel_launch(void* const* d_in, const int* in_sizes, int n_in,
                              void* d_out, int out_size, void* d_ws, size_t ws_size,
                              hipStream_t stream) {
    const float* xre = (const float*)d_in[0];
    const float* xim = (const float*)d_in[1];
    const float* ms  = (const float*)d_in[2];
    const float* mn  = (const float*)d_in[3];
    const int real_only = (out_size < (int)(2 * NB * NC * (size_t)NF * NT)) ? 1 : 0;
    hipLaunchKernelGGL(pmwf_kernel, dim3(NB * NF), dim3(256), 0, stream,
                       xre, xim, ms, mn, (float*)d_out, real_only);
}